// Round 1
// baseline (788.453 us; speedup 1.0000x reference)
//
#include <hip/hip_runtime.h>
#include <stdint.h>

typedef __attribute__((ext_vector_type(8))) __bf16 bf16x8;
typedef __attribute__((ext_vector_type(4))) float f32x4;
typedef unsigned short u16;

#define D_MODEL 1024
#define D_FF 4096
#define SEQ 2048
#define NHEAD 16
#define DH 64
#define MROWS 8192
#define LDST 72  // LDS row stride (elems): 144B = 36 dwords == 4 mod 32 banks -> ~2-way (free)

__device__ __forceinline__ u16 f2bf(float f) {
  union { float f; unsigned u; } v; v.f = f;
  unsigned r = v.u + 0x7fffu + ((v.u >> 16) & 1u);
  return (u16)(r >> 16);
}

// ---------------- weight f32 [K][N] -> bf16 transposed [N][K] ----------------
__global__ __launch_bounds__(256)
void wconv_kernel(const float* __restrict__ W, u16* __restrict__ Wt, int K, int N) {
  __shared__ u16 t[32][33];
  const int tid = threadIdx.x, tx = tid & 31, ty = tid >> 5;
  const int n0 = blockIdx.x * 32, k0 = blockIdx.y * 32;
#pragma unroll
  for (int i = 0; i < 4; ++i) {
    int k = ty + i * 8;
    t[k][tx] = f2bf(W[(size_t)(k0 + k) * N + n0 + tx]);
  }
  __syncthreads();
#pragma unroll
  for (int i = 0; i < 4; ++i) {
    int n = ty + i * 8;
    Wt[(size_t)(n0 + n) * K + k0 + tx] = t[tx][n];
  }
}

// ---------------- layernorm: f32 [row][1024] -> bf16 ----------------
__global__ __launch_bounds__(256)
void ln_kernel(const float* __restrict__ x, u16* __restrict__ out,
               const float* __restrict__ g, const float* __restrict__ beta) {
  const int row = blockIdx.x, tid = threadIdx.x;
  const float4 v = reinterpret_cast<const float4*>(x + (size_t)row * D_MODEL)[tid];
  float s = v.x + v.y + v.z + v.w;
#pragma unroll
  for (int off = 32; off; off >>= 1) s += __shfl_down(s, off);
  __shared__ float red[8];
  if ((tid & 63) == 0) red[tid >> 6] = s;
  __syncthreads();
  const float mu = (red[0] + red[1] + red[2] + red[3]) * (1.0f / D_MODEL);
  const float dx = v.x - mu, dy = v.y - mu, dz = v.z - mu, dw = v.w - mu;
  float sq = dx * dx + dy * dy + dz * dz + dw * dw;
#pragma unroll
  for (int off = 32; off; off >>= 1) sq += __shfl_down(sq, off);
  if ((tid & 63) == 0) red[4 + (tid >> 6)] = sq;
  __syncthreads();
  const float var = (red[4] + red[5] + red[6] + red[7]) * (1.0f / D_MODEL);
  const float rs = rsqrtf(var + 1e-5f);
  const float4 gv = reinterpret_cast<const float4*>(g)[tid];
  const float4 bv = reinterpret_cast<const float4*>(beta)[tid];
  ushort4 ov;
  ov.x = f2bf(dx * rs * gv.x + bv.x);
  ov.y = f2bf(dy * rs * gv.y + bv.y);
  ov.z = f2bf(dz * rs * gv.z + bv.z);
  ov.w = f2bf(dw * rs * gv.w + bv.w);
  reinterpret_cast<ushort4*>(out + (size_t)row * D_MODEL)[tid] = ov;
}

// ---------------- TN GEMM: C[M,N] = A[M,K] * Bt[N,K]^T, bf16 in, epilogues ----
// EPI 0: C -> bf16 out
// EPI 1: C + bias[col] + res[idx] -> f32 out   (res may alias out)
// EPI 2: relu(C + bias[col]) -> bf16 out
template <int EPI>
__global__ __launch_bounds__(256)
void gemm_kernel(const u16* __restrict__ A, const u16* __restrict__ Bt,
                 int N, int K,
                 const float* __restrict__ bias,
                 const float* __restrict__ res,
                 float* __restrict__ outf, u16* __restrict__ outb) {
  __shared__ u16 Al[128 * LDST];
  __shared__ u16 Bl[128 * LDST];
  const int tid = threadIdx.x;
  const int lane = tid & 63, wave = tid >> 6, g8 = lane >> 4, l16 = lane & 15;
  const int wr = wave >> 1, wc = wave & 1;
  const int mBase = blockIdx.y * 128, nBase = blockIdx.x * 128;
  const int srow = tid >> 3, scol = (tid & 7) * 8;

  f32x4 acc[4][4];
#pragma unroll
  for (int i = 0; i < 4; ++i)
#pragma unroll
    for (int j = 0; j < 4; ++j) acc[i][j] = f32x4{0.f, 0.f, 0.f, 0.f};

  for (int k0 = 0; k0 < K; k0 += 64) {
#pragma unroll
    for (int i = 0; i < 4; ++i) {
      const int row = srow + i * 32;
      *reinterpret_cast<int4*>(&Al[row * LDST + scol]) =
          *reinterpret_cast<const int4*>(A + (size_t)(mBase + row) * K + k0 + scol);
      *reinterpret_cast<int4*>(&Bl[row * LDST + scol]) =
          *reinterpret_cast<const int4*>(Bt + (size_t)(nBase + row) * K + k0 + scol);
    }
    __syncthreads();
#pragma unroll
    for (int ks = 0; ks < 2; ++ks) {
      bf16x8 af[4], bfr[4];
#pragma unroll
      for (int i = 0; i < 4; ++i) {
        af[i] = *reinterpret_cast<const bf16x8*>(&Al[(wr * 64 + i * 16 + l16) * LDST + ks * 32 + g8 * 8]);
        bfr[i] = *reinterpret_cast<const bf16x8*>(&Bl[(wc * 64 + i * 16 + l16) * LDST + ks * 32 + g8 * 8]);
      }
#pragma unroll
      for (int i = 0; i < 4; ++i)
#pragma unroll
        for (int j = 0; j < 4; ++j)
          acc[i][j] = __builtin_amdgcn_mfma_f32_16x16x32_bf16(af[i], bfr[j], acc[i][j], 0, 0, 0);
    }
    __syncthreads();
  }

#pragma unroll
  for (int i = 0; i < 4; ++i)
#pragma unroll
    for (int j = 0; j < 4; ++j) {
      const int col = nBase + wc * 64 + j * 16 + l16;
      float bv = 0.f;
      if (EPI != 0) bv = bias[col];
#pragma unroll
      for (int r = 0; r < 4; ++r) {
        const int row = mBase + wr * 64 + i * 16 + g8 * 4 + r;
        const size_t idx = (size_t)row * N + col;
        const float vv = acc[i][j][r];
        if (EPI == 0) {
          outb[idx] = f2bf(vv);
        } else if (EPI == 1) {
          outf[idx] = vv + bv + res[idx];
        } else {
          const float tv = vv + bv;
          outb[idx] = f2bf(tv > 0.f ? tv : 0.f);
        }
      }
    }
}

// ---------------- flash attention, 4 waves x 32 q-rows, KV tile 64 ----------------
__global__ __launch_bounds__(256)
void attn_kernel(const u16* __restrict__ qb, const u16* __restrict__ kb,
                 const u16* __restrict__ vb, u16* __restrict__ ctx) {
  __shared__ u16 Kl[64 * LDST];
  __shared__ u16 Vl[64 * LDST];
  __shared__ u16 Pl[4][32 * LDST];
  const int tid = threadIdx.x;
  const int lane = tid & 63, wave = tid >> 6, g8 = lane >> 4, l16 = lane & 15;
  const int b = blockIdx.y >> 4, h = blockIdx.y & 15;
  const int q0 = blockIdx.x * 128 + wave * 32;
  const size_t rowB = (size_t)b * SEQ;
  const int colH = h * DH;

  bf16x8 qf[2][2];
#pragma unroll
  for (int m = 0; m < 2; ++m)
#pragma unroll
    for (int ks = 0; ks < 2; ++ks)
      qf[m][ks] = *reinterpret_cast<const bf16x8*>(
          qb + (rowB + q0 + m * 16 + l16) * D_MODEL + colH + ks * 32 + g8 * 8);

  float mi_[2][4], li[2][4];
  f32x4 o[2][4];
#pragma unroll
  for (int m = 0; m < 2; ++m)
#pragma unroll
    for (int r = 0; r < 4; ++r) { mi_[m][r] = -1e30f; li[m][r] = 0.f; }
#pragma unroll
  for (int m = 0; m < 2; ++m)
#pragma unroll
    for (int nt = 0; nt < 4; ++nt) o[m][nt] = f32x4{0.f, 0.f, 0.f, 0.f};

  const int srow = tid >> 3, scol = (tid & 7) * 8;

  for (int t0 = 0; t0 < SEQ; t0 += 64) {
#pragma unroll
    for (int i = 0; i < 2; ++i) {
      const int row = srow + i * 32;
      *reinterpret_cast<int4*>(&Kl[row * LDST + scol]) =
          *reinterpret_cast<const int4*>(kb + (rowB + t0 + row) * D_MODEL + colH + scol);
      *reinterpret_cast<int4*>(&Vl[row * LDST + scol]) =
          *reinterpret_cast<const int4*>(vb + (rowB + t0 + row) * D_MODEL + colH + scol);
    }
    __syncthreads();

    // S = Q K^T
    f32x4 s[2][4];
#pragma unroll
    for (int m = 0; m < 2; ++m)
#pragma unroll
      for (int nt = 0; nt < 4; ++nt) s[m][nt] = f32x4{0.f, 0.f, 0.f, 0.f};
#pragma unroll
    for (int nt = 0; nt < 4; ++nt) {
      const bf16x8 kf0 = *reinterpret_cast<const bf16x8*>(&Kl[(nt * 16 + l16) * LDST + g8 * 8]);
      const bf16x8 kf1 = *reinterpret_cast<const bf16x8*>(&Kl[(nt * 16 + l16) * LDST + 32 + g8 * 8]);
#pragma unroll
      for (int m = 0; m < 2; ++m) {
        s[m][nt] = __builtin_amdgcn_mfma_f32_16x16x32_bf16(qf[m][0], kf0, s[m][nt], 0, 0, 0);
        s[m][nt] = __builtin_amdgcn_mfma_f32_16x16x32_bf16(qf[m][1], kf1, s[m][nt], 0, 0, 0);
      }
    }

    // online softmax (row = g8*4+r, col = l16 within 16-lane group)
#pragma unroll
    for (int m = 0; m < 2; ++m) {
#pragma unroll
      for (int nt = 0; nt < 4; ++nt) s[m][nt] *= 0.125f;
      float al[4];
#pragma unroll
      for (int r = 0; r < 4; ++r) {
        float mx = fmaxf(fmaxf(s[m][0][r], s[m][1][r]), fmaxf(s[m][2][r], s[m][3][r]));
#pragma unroll
        for (int msk = 1; msk < 16; msk <<= 1) mx = fmaxf(mx, __shfl_xor(mx, msk));
        const float mnew = fmaxf(mi_[m][r], mx);
        al[r] = __expf(mi_[m][r] - mnew);
        mi_[m][r] = mnew;
        float sum = 0.f;
#pragma unroll
        for (int nt = 0; nt < 4; ++nt) {
          const float p = __expf(s[m][nt][r] - mnew);
          sum += p;
          Pl[wave][(m * 16 + g8 * 4 + r) * LDST + nt * 16 + l16] = f2bf(p);
        }
#pragma unroll
        for (int msk = 1; msk < 16; msk <<= 1) sum += __shfl_xor(sum, msk);
        li[m][r] = li[m][r] * al[r] + sum;
      }
#pragma unroll
      for (int nt = 0; nt < 4; ++nt) {
        f32x4 t = o[m][nt];
        t[0] *= al[0]; t[1] *= al[1]; t[2] *= al[2]; t[3] *= al[3];
        o[m][nt] = t;
      }
    }

    // O += P V  (P re-fragmented via per-wave LDS round-trip)
    bf16x8 pf[2][2];
#pragma unroll
    for (int m = 0; m < 2; ++m)
#pragma unroll
      for (int ks = 0; ks < 2; ++ks)
        pf[m][ks] = *reinterpret_cast<const bf16x8*>(&Pl[wave][(m * 16 + l16) * LDST + ks * 32 + g8 * 8]);
#pragma unroll
    for (int nt = 0; nt < 4; ++nt) {
      bf16x8 vf[2];
#pragma unroll
      for (int ks = 0; ks < 2; ++ks)
#pragma unroll
        for (int j = 0; j < 8; ++j) {
          const u16 bits = Vl[(ks * 32 + g8 * 8 + j) * LDST + nt * 16 + l16];
          vf[ks][j] = __builtin_bit_cast(__bf16, bits);
        }
#pragma unroll
      for (int m = 0; m < 2; ++m) {
        o[m][nt] = __builtin_amdgcn_mfma_f32_16x16x32_bf16(pf[m][0], vf[0], o[m][nt], 0, 0, 0);
        o[m][nt] = __builtin_amdgcn_mfma_f32_16x16x32_bf16(pf[m][1], vf[1], o[m][nt], 0, 0, 0);
      }
    }
    __syncthreads();
  }

#pragma unroll
  for (int m = 0; m < 2; ++m)
#pragma unroll
    for (int nt = 0; nt < 4; ++nt)
#pragma unroll
      for (int r = 0; r < 4; ++r) {
        const float v = o[m][nt][r] / li[m][r];
        ctx[(rowB + q0 + m * 16 + g8 * 4 + r) * D_MODEL + colH + nt * 16 + l16] = f2bf(v);
      }
}

extern "C" void kernel_launch(void* const* d_in, const int* in_sizes, int n_in,
                              void* d_out, int out_size, void* d_ws, size_t ws_size,
                              hipStream_t stream) {
  const float* x   = (const float*)d_in[0];
  const float* wq  = (const float*)d_in[1];
  const float* wk  = (const float*)d_in[2];
  const float* wv  = (const float*)d_in[3];
  const float* wo  = (const float*)d_in[4];
  const float* bo  = (const float*)d_in[5];
  const float* l1g = (const float*)d_in[6];
  const float* l1b = (const float*)d_in[7];
  const float* l2g = (const float*)d_in[8];
  const float* l2b = (const float*)d_in[9];
  const float* w1  = (const float*)d_in[10];
  const float* b1  = (const float*)d_in[11];
  const float* w2  = (const float*)d_in[12];
  const float* b2  = (const float*)d_in[13];
  float* outp = (float*)d_out;

  uint8_t* ws = (uint8_t*)d_ws;
  const size_t MB = 1024 * 1024;
  // workspace layout (120 MB total, with lifetime-based overlays):
  u16* wqt  = (u16*)(ws + 0 * MB);   // [1024][1024]
  u16* wkt  = (u16*)(ws + 2 * MB);
  u16* wvt  = (u16*)(ws + 4 * MB);
  u16* wot  = (u16*)(ws + 6 * MB);
  u16* w1t  = (u16*)(ws + 8 * MB);   // [4096][1024]
  u16* w2t  = (u16*)(ws + 16 * MB);  // [1024][4096]
  u16* xn   = (u16*)(ws + 24 * MB);  // [8192][1024]; reused as ctx after QKV
  u16* qbuf = (u16*)(ws + 40 * MB);  // [8192][1024]; reused as h after attention
  u16* kbuf = (u16*)(ws + 56 * MB);  // [8192][1024]
  u16* vbuf = (u16*)(ws + 72 * MB);  // [8192][1024]
  u16* ctx  = xn;
  u16* hbuf = qbuf;
  u16* ffh  = kbuf;                  // [8192][4096] overlays kbuf..(56+64) MB

  dim3 blk(256);

  // weights -> bf16 transposed
  wconv_kernel<<<dim3(32, 32), blk, 0, stream>>>(wq, wqt, 1024, 1024);
  wconv_kernel<<<dim3(32, 32), blk, 0, stream>>>(wk, wkt, 1024, 1024);
  wconv_kernel<<<dim3(32, 32), blk, 0, stream>>>(wv, wvt, 1024, 1024);
  wconv_kernel<<<dim3(32, 32), blk, 0, stream>>>(wo, wot, 1024, 1024);
  wconv_kernel<<<dim3(128, 32), blk, 0, stream>>>(w1, w1t, 1024, 4096);
  wconv_kernel<<<dim3(32, 128), blk, 0, stream>>>(w2, w2t, 4096, 1024);

  // xn = LN1(x)
  ln_kernel<<<MROWS, blk, 0, stream>>>(x, xn, l1g, l1b);

  // q, k, v projections
  gemm_kernel<0><<<dim3(8, 64), blk, 0, stream>>>(xn, wqt, 1024, 1024, nullptr, nullptr, nullptr, qbuf);
  gemm_kernel<0><<<dim3(8, 64), blk, 0, stream>>>(xn, wkt, 1024, 1024, nullptr, nullptr, nullptr, kbuf);
  gemm_kernel<0><<<dim3(8, 64), blk, 0, stream>>>(xn, wvt, 1024, 1024, nullptr, nullptr, nullptr, vbuf);

  // ctx = softmax(QK^T/8) V
  attn_kernel<<<dim3(16, 64), blk, 0, stream>>>(qbuf, kbuf, vbuf, ctx);

  // xt = x + ctx@wo + bo   (-> d_out, f32)
  gemm_kernel<1><<<dim3(8, 64), blk, 0, stream>>>(ctx, wot, 1024, 1024, bo, x, outp, nullptr);

  // h = LN2(xt)
  ln_kernel<<<MROWS, blk, 0, stream>>>(outp, hbuf, l2g, l2b);

  // ffh = relu(h@w1 + b1)
  gemm_kernel<2><<<dim3(32, 64), blk, 0, stream>>>(hbuf, w1t, 4096, 1024, b1, nullptr, nullptr, ffh);

  // out = xt + ffh@w2 + b2  (in-place on d_out)
  gemm_kernel<1><<<dim3(8, 64), blk, 0, stream>>>(ffh, w2t, 1024, 4096, b2, outp, outp, nullptr);
}

// Round 2
// 765.154 us; speedup vs baseline: 1.0304x; 1.0304x over previous
//
#include <hip/hip_runtime.h>
#include <stdint.h>

typedef __attribute__((ext_vector_type(8))) __bf16 bf16x8;
typedef __attribute__((ext_vector_type(4))) float f32x4;
typedef unsigned short u16;

#define D_MODEL 1024
#define D_FF 4096
#define SEQ 2048
#define NHEAD 16
#define DH 64
#define MROWS 8192
#define LDST 72  // attn LDS row stride (elems): 144B == 4 dwords mod 32 banks -> b128 reads hit all 32 banks evenly

__device__ __forceinline__ u16 f2bf(float f) {
  union { float f; unsigned u; } v; v.f = f;
  unsigned r = v.u + 0x7fffu + ((v.u >> 16) & 1u);
  return (u16)(r >> 16);
}

// async global->LDS, 16B per lane; lds dest must be wave-uniform base (+lane*16 implicit)
__device__ __forceinline__ void gload16(const u16* g, u16* l) {
  __builtin_amdgcn_global_load_lds((const __attribute__((address_space(1))) void*)(g),
                                   (__attribute__((address_space(3))) void*)(l),
                                   16, 0, 0);
}

// ---------------- weight f32 [K][N] -> bf16 transposed [N][K] ----------------
__global__ __launch_bounds__(256)
void wconv_kernel(const float* __restrict__ W, u16* __restrict__ Wt, int K, int N) {
  __shared__ u16 t[32][33];
  const int tid = threadIdx.x, tx = tid & 31, ty = tid >> 5;
  const int n0 = blockIdx.x * 32, k0 = blockIdx.y * 32;
#pragma unroll
  for (int i = 0; i < 4; ++i) {
    int k = ty + i * 8;
    t[k][tx] = f2bf(W[(size_t)(k0 + k) * N + n0 + tx]);
  }
  __syncthreads();
#pragma unroll
  for (int i = 0; i < 4; ++i) {
    int n = ty + i * 8;
    Wt[(size_t)(n0 + n) * K + k0 + tx] = t[tx][n];
  }
}

// ---------------- layernorm: f32 [row][1024] -> bf16 ----------------
__global__ __launch_bounds__(256)
void ln_kernel(const float* __restrict__ x, u16* __restrict__ out,
               const float* __restrict__ g, const float* __restrict__ beta) {
  const int row = blockIdx.x, tid = threadIdx.x;
  const float4 v = reinterpret_cast<const float4*>(x + (size_t)row * D_MODEL)[tid];
  float s = v.x + v.y + v.z + v.w;
#pragma unroll
  for (int off = 32; off; off >>= 1) s += __shfl_down(s, off);
  __shared__ float red[8];
  if ((tid & 63) == 0) red[tid >> 6] = s;
  __syncthreads();
  const float mu = (red[0] + red[1] + red[2] + red[3]) * (1.0f / D_MODEL);
  const float dx = v.x - mu, dy = v.y - mu, dz = v.z - mu, dw = v.w - mu;
  float sq = dx * dx + dy * dy + dz * dz + dw * dw;
#pragma unroll
  for (int off = 32; off; off >>= 1) sq += __shfl_down(sq, off);
  if ((tid & 63) == 0) red[4 + (tid >> 6)] = sq;
  __syncthreads();
  const float var = (red[4] + red[5] + red[6] + red[7]) * (1.0f / D_MODEL);
  const float rs = rsqrtf(var + 1e-5f);
  const float4 gv = reinterpret_cast<const float4*>(g)[tid];
  const float4 bv = reinterpret_cast<const float4*>(beta)[tid];
  ushort4 ov;
  ov.x = f2bf(dx * rs * gv.x + bv.x);
  ov.y = f2bf(dy * rs * gv.y + bv.y);
  ov.z = f2bf(dz * rs * gv.z + bv.z);
  ov.w = f2bf(dw * rs * gv.w + bv.w);
  reinterpret_cast<ushort4*>(out + (size_t)row * D_MODEL)[tid] = ov;
}

// ---------------- TN GEMM: C[M,N] = A[M,K] * Bt[N,K]^T, bf16 in, epilogues ----
// EPI 0: C -> bf16 out (row-major [M][N])
// EPI 1: C + bias[col] + res[idx] -> f32 out   (res may alias out)
// EPI 2: relu(C + bias[col]) -> bf16 out
// EPI 3: C -> bf16 out TRANSPOSED per batch: out[(b*1024+col)*2048 + s], b=row>>11, s=row&2047
template <int EPI>
__global__ __launch_bounds__(256)
void gemm_kernel(const u16* __restrict__ A, const u16* __restrict__ Bt,
                 int N, int K,
                 const float* __restrict__ bias,
                 const float* __restrict__ res,
                 float* __restrict__ outf, u16* __restrict__ outb) {
  __shared__ u16 Al[128 * 64];
  __shared__ u16 Bl[128 * 64];
  const int tid = threadIdx.x;
  const int lane = tid & 63, wave = tid >> 6, g8 = lane >> 4, l16 = lane & 15;
  const int wr = wave >> 1, wc = wave & 1;
  const int mBase = blockIdx.y * 128, nBase = blockIdx.x * 128;
  // staging decomposition: per global_load_lds issue, 64 lanes x 16B = 8 rows of 64 elems
  const int ldRow = lane >> 3;        // 0..7 within 8-row group
  const int ldCol = (lane & 7) * 8;   // 8 elems

  f32x4 acc[4][4];
#pragma unroll
  for (int i = 0; i < 4; ++i)
#pragma unroll
    for (int j = 0; j < 4; ++j) acc[i][j] = f32x4{0.f, 0.f, 0.f, 0.f};

  for (int k0 = 0; k0 < K; k0 += 64) {
    // wave w stages A rows [w*32, w*32+32) and B rows same, 4 issues each
#pragma unroll
    for (int i = 0; i < 4; ++i) {
      const int row = wave * 32 + i * 8 + ldRow;
      gload16(A + (size_t)(mBase + row) * K + k0 + ldCol, &Al[(wave * 32 + i * 8) * 64]);
      gload16(Bt + (size_t)(nBase + row) * K + k0 + ldCol, &Bl[(wave * 32 + i * 8) * 64]);
    }
    __syncthreads();
#pragma unroll
    for (int ks = 0; ks < 2; ++ks) {
      bf16x8 af[4], bfr[4];
#pragma unroll
      for (int i = 0; i < 4; ++i) {
        af[i] = *reinterpret_cast<const bf16x8*>(&Al[(wr * 64 + i * 16 + l16) * 64 + ks * 32 + g8 * 8]);
        bfr[i] = *reinterpret_cast<const bf16x8*>(&Bl[(wc * 64 + i * 16 + l16) * 64 + ks * 32 + g8 * 8]);
      }
#pragma unroll
      for (int i = 0; i < 4; ++i)
#pragma unroll
        for (int j = 0; j < 4; ++j)
          acc[i][j] = __builtin_amdgcn_mfma_f32_16x16x32_bf16(af[i], bfr[j], acc[i][j], 0, 0, 0);
    }
    __syncthreads();
  }

#pragma unroll
  for (int i = 0; i < 4; ++i)
#pragma unroll
    for (int j = 0; j < 4; ++j) {
      const int col = nBase + wc * 64 + j * 16 + l16;
      float bv = 0.f;
      if (EPI == 1 || EPI == 2) bv = bias[col];
      if (EPI == 3) {
        const int s0 = mBase + wr * 64 + i * 16 + g8 * 4;
        const int bi = s0 >> 11, s = s0 & 2047;
        ushort4 pk;
        pk.x = f2bf(acc[i][j][0]);
        pk.y = f2bf(acc[i][j][1]);
        pk.z = f2bf(acc[i][j][2]);
        pk.w = f2bf(acc[i][j][3]);
        *reinterpret_cast<ushort4*>(outb + ((size_t)(bi << 10) + col) * SEQ + s) = pk;
      } else {
#pragma unroll
        for (int r = 0; r < 4; ++r) {
          const int row = mBase + wr * 64 + i * 16 + g8 * 4 + r;
          const size_t idx = (size_t)row * N + col;
          const float vv = acc[i][j][r];
          if (EPI == 0) {
            outb[idx] = f2bf(vv);
          } else if (EPI == 1) {
            outf[idx] = vv + bv + res[idx];
          } else {
            const float tv = vv + bv;
            outb[idx] = f2bf(tv > 0.f ? tv : 0.f);
          }
        }
      }
    }
}

// ---------------- flash attention, 4 waves x 32 q-rows, KV tile 64 ----------------
// vb is V TRANSPOSED per batch: vb[(b*1024 + h*64 + d)*2048 + s]
__global__ __launch_bounds__(256)
void attn_kernel(const u16* __restrict__ qb, const u16* __restrict__ kb,
                 const u16* __restrict__ vb, u16* __restrict__ ctx) {
  __shared__ u16 Kl[64 * LDST];
  __shared__ u16 Vl[64 * LDST];  // V^T tile: Vl[d][t]
  __shared__ u16 Pl[4][32 * LDST];
  const int tid = threadIdx.x;
  const int lane = tid & 63, wave = tid >> 6, g8 = lane >> 4, l16 = lane & 15;
  const int b = blockIdx.y >> 4, h = blockIdx.y & 15;
  const int q0 = blockIdx.x * 128 + wave * 32;
  const size_t rowB = (size_t)b * SEQ;
  const int colH = h * DH;
  const size_t vtBase = (size_t)(b * 1024 + colH) * SEQ;  // row d of V^T at vtBase + d*SEQ

  bf16x8 qf[2][2];
#pragma unroll
  for (int m = 0; m < 2; ++m)
#pragma unroll
    for (int ks = 0; ks < 2; ++ks)
      qf[m][ks] = *reinterpret_cast<const bf16x8*>(
          qb + (rowB + q0 + m * 16 + l16) * D_MODEL + colH + ks * 32 + g8 * 8);

  float mi_[2][4], li[2][4];
  f32x4 o[2][4];
#pragma unroll
  for (int m = 0; m < 2; ++m)
#pragma unroll
    for (int r = 0; r < 4; ++r) { mi_[m][r] = -1e30f; li[m][r] = 0.f; }
#pragma unroll
  for (int m = 0; m < 2; ++m)
#pragma unroll
    for (int nt = 0; nt < 4; ++nt) o[m][nt] = f32x4{0.f, 0.f, 0.f, 0.f};

  const int srow = tid >> 3, scol = (tid & 7) * 8;

  for (int t0 = 0; t0 < SEQ; t0 += 64) {
#pragma unroll
    for (int i = 0; i < 2; ++i) {
      const int row = srow + i * 32;
      // K tile row-major: Kl[t][d]
      *reinterpret_cast<int4*>(&Kl[row * LDST + scol]) =
          *reinterpret_cast<const int4*>(kb + (rowB + t0 + row) * D_MODEL + colH + scol);
      // V^T tile: Vl[d][t] from transposed global V
      *reinterpret_cast<int4*>(&Vl[row * LDST + scol]) =
          *reinterpret_cast<const int4*>(vb + vtBase + (size_t)row * SEQ + t0 + scol);
    }
    __syncthreads();

    // S = Q K^T
    f32x4 s[2][4];
#pragma unroll
    for (int m = 0; m < 2; ++m)
#pragma unroll
      for (int nt = 0; nt < 4; ++nt) s[m][nt] = f32x4{0.f, 0.f, 0.f, 0.f};
#pragma unroll
    for (int nt = 0; nt < 4; ++nt) {
      const bf16x8 kf0 = *reinterpret_cast<const bf16x8*>(&Kl[(nt * 16 + l16) * LDST + g8 * 8]);
      const bf16x8 kf1 = *reinterpret_cast<const bf16x8*>(&Kl[(nt * 16 + l16) * LDST + 32 + g8 * 8]);
#pragma unroll
      for (int m = 0; m < 2; ++m) {
        s[m][nt] = __builtin_amdgcn_mfma_f32_16x16x32_bf16(qf[m][0], kf0, s[m][nt], 0, 0, 0);
        s[m][nt] = __builtin_amdgcn_mfma_f32_16x16x32_bf16(qf[m][1], kf1, s[m][nt], 0, 0, 0);
      }
    }

    // online softmax (row = g8*4+r, col = l16 within 16-lane group)
#pragma unroll
    for (int m = 0; m < 2; ++m) {
#pragma unroll
      for (int nt = 0; nt < 4; ++nt) s[m][nt] *= 0.125f;
      float al[4];
#pragma unroll
      for (int r = 0; r < 4; ++r) {
        float mx = fmaxf(fmaxf(s[m][0][r], s[m][1][r]), fmaxf(s[m][2][r], s[m][3][r]));
#pragma unroll
        for (int msk = 1; msk < 16; msk <<= 1) mx = fmaxf(mx, __shfl_xor(mx, msk));
        const float mnew = fmaxf(mi_[m][r], mx);
        al[r] = __expf(mi_[m][r] - mnew);
        mi_[m][r] = mnew;
        float sum = 0.f;
#pragma unroll
        for (int nt = 0; nt < 4; ++nt) {
          const float p = __expf(s[m][nt][r] - mnew);
          sum += p;
          Pl[wave][(m * 16 + g8 * 4 + r) * LDST + nt * 16 + l16] = f2bf(p);
        }
#pragma unroll
        for (int msk = 1; msk < 16; msk <<= 1) sum += __shfl_xor(sum, msk);
        li[m][r] = li[m][r] * al[r] + sum;
      }
#pragma unroll
      for (int nt = 0; nt < 4; ++nt) {
        f32x4 t = o[m][nt];
        t[0] *= al[0]; t[1] *= al[1]; t[2] *= al[2]; t[3] *= al[3];
        o[m][nt] = t;
      }
    }

    // O += P V  (P re-fragmented via per-wave LDS; V fragments now vector reads from V^T)
    bf16x8 pf[2][2];
#pragma unroll
    for (int m = 0; m < 2; ++m)
#pragma unroll
      for (int ks = 0; ks < 2; ++ks)
        pf[m][ks] = *reinterpret_cast<const bf16x8*>(&Pl[wave][(m * 16 + l16) * LDST + ks * 32 + g8 * 8]);
#pragma unroll
    for (int nt = 0; nt < 4; ++nt) {
      // B-frag: V[k=t][n=d] = Vl[d = nt*16+l16][t = ks*32 + g8*8 + j]
      const bf16x8 vf0 = *reinterpret_cast<const bf16x8*>(&Vl[(nt * 16 + l16) * LDST + g8 * 8]);
      const bf16x8 vf1 = *reinterpret_cast<const bf16x8*>(&Vl[(nt * 16 + l16) * LDST + 32 + g8 * 8]);
#pragma unroll
      for (int m = 0; m < 2; ++m) {
        o[m][nt] = __builtin_amdgcn_mfma_f32_16x16x32_bf16(pf[m][0], vf0, o[m][nt], 0, 0, 0);
        o[m][nt] = __builtin_amdgcn_mfma_f32_16x16x32_bf16(pf[m][1], vf1, o[m][nt], 0, 0, 0);
      }
    }
    __syncthreads();
  }

#pragma unroll
  for (int m = 0; m < 2; ++m)
#pragma unroll
    for (int nt = 0; nt < 4; ++nt)
#pragma unroll
      for (int r = 0; r < 4; ++r) {
        const float v = o[m][nt][r] / li[m][r];
        ctx[(rowB + q0 + m * 16 + g8 * 4 + r) * D_MODEL + colH + nt * 16 + l16] = f2bf(v);
      }
}

extern "C" void kernel_launch(void* const* d_in, const int* in_sizes, int n_in,
                              void* d_out, int out_size, void* d_ws, size_t ws_size,
                              hipStream_t stream) {
  const float* x   = (const float*)d_in[0];
  const float* wq  = (const float*)d_in[1];
  const float* wk  = (const float*)d_in[2];
  const float* wv  = (const float*)d_in[3];
  const float* wo  = (const float*)d_in[4];
  const float* bo  = (const float*)d_in[5];
  const float* l1g = (const float*)d_in[6];
  const float* l1b = (const float*)d_in[7];
  const float* l2g = (const float*)d_in[8];
  const float* l2b = (const float*)d_in[9];
  const float* w1  = (const float*)d_in[10];
  const float* b1  = (const float*)d_in[11];
  const float* w2  = (const float*)d_in[12];
  const float* b2  = (const float*)d_in[13];
  float* outp = (float*)d_out;

  uint8_t* ws = (uint8_t*)d_ws;
  const size_t MB = 1024 * 1024;
  // workspace layout (120 MB total, lifetime-based overlays):
  u16* wqt   = (u16*)(ws + 0 * MB);   // [1024][1024]
  u16* wkt   = (u16*)(ws + 2 * MB);
  u16* wvt   = (u16*)(ws + 4 * MB);
  u16* wot   = (u16*)(ws + 6 * MB);
  u16* w1t   = (u16*)(ws + 8 * MB);   // [4096][1024]
  u16* w2t   = (u16*)(ws + 16 * MB);  // [1024][4096]
  u16* xn    = (u16*)(ws + 24 * MB);  // [8192][1024]; reused as ctx after QKV
  u16* qbuf  = (u16*)(ws + 40 * MB);  // [8192][1024]; reused as h after attention
  u16* kbuf  = (u16*)(ws + 56 * MB);  // [8192][1024]
  u16* vbufT = (u16*)(ws + 72 * MB);  // [4][1024][2048] transposed V
  u16* ctx   = xn;
  u16* hbuf  = qbuf;
  u16* ffh   = kbuf;                  // [8192][4096] overlays kbuf..(56+64) MB (vbufT dead by then)

  dim3 blk(256);

  // weights -> bf16 transposed
  wconv_kernel<<<dim3(32, 32), blk, 0, stream>>>(wq, wqt, 1024, 1024);
  wconv_kernel<<<dim3(32, 32), blk, 0, stream>>>(wk, wkt, 1024, 1024);
  wconv_kernel<<<dim3(32, 32), blk, 0, stream>>>(wv, wvt, 1024, 1024);
  wconv_kernel<<<dim3(32, 32), blk, 0, stream>>>(wo, wot, 1024, 1024);
  wconv_kernel<<<dim3(128, 32), blk, 0, stream>>>(w1, w1t, 1024, 4096);
  wconv_kernel<<<dim3(32, 128), blk, 0, stream>>>(w2, w2t, 4096, 1024);

  // xn = LN1(x)
  ln_kernel<<<MROWS, blk, 0, stream>>>(x, xn, l1g, l1b);

  // q, k projections row-major; v projection written transposed per head
  gemm_kernel<0><<<dim3(8, 64), blk, 0, stream>>>(xn, wqt, 1024, 1024, nullptr, nullptr, nullptr, qbuf);
  gemm_kernel<0><<<dim3(8, 64), blk, 0, stream>>>(xn, wkt, 1024, 1024, nullptr, nullptr, nullptr, kbuf);
  gemm_kernel<3><<<dim3(8, 64), blk, 0, stream>>>(xn, wvt, 1024, 1024, nullptr, nullptr, nullptr, vbufT);

  // ctx = softmax(QK^T/8) V
  attn_kernel<<<dim3(16, 64), blk, 0, stream>>>(qbuf, kbuf, vbufT, ctx);

  // xt = x + ctx@wo + bo   (-> d_out, f32)
  gemm_kernel<1><<<dim3(8, 64), blk, 0, stream>>>(ctx, wot, 1024, 1024, bo, x, outp, nullptr);

  // h = LN2(xt)
  ln_kernel<<<MROWS, blk, 0, stream>>>(outp, hbuf, l2g, l2b);

  // ffh = relu(h@w1 + b1)
  gemm_kernel<2><<<dim3(32, 64), blk, 0, stream>>>(hbuf, w1t, 4096, 1024, b1, nullptr, nullptr, ffh);

  // out = xt + ffh@w2 + b2  (in-place on d_out)
  gemm_kernel<1><<<dim3(8, 64), blk, 0, stream>>>(ffh, w2t, 1024, 4096, b2, outp, outp, nullptr);
}

// Round 3
// 664.689 us; speedup vs baseline: 1.1862x; 1.1511x over previous
//
#include <hip/hip_runtime.h>
#include <stdint.h>

typedef __attribute__((ext_vector_type(8))) __bf16 bf16x8;
typedef __attribute__((ext_vector_type(4))) float f32x4;
typedef unsigned short u16;

#define D_MODEL 1024
#define D_FF 4096
#define SEQ 2048
#define NHEAD 16
#define DH 64
#define MROWS 8192
#define LDST 72  // attn LDS row stride (elems): 144B == 4 dwords mod 32 banks -> b128 reads hit all 32 banks evenly

__device__ __forceinline__ u16 f2bf(float f) {
  union { float f; unsigned u; } v; v.f = f;
  unsigned r = v.u + 0x7fffu + ((v.u >> 16) & 1u);
  return (u16)(r >> 16);
}

// async global->LDS, 16B per lane; lds dest must be wave-uniform base (+lane*16 implicit)
__device__ __forceinline__ void gload16(const u16* g, u16* l) {
  __builtin_amdgcn_global_load_lds((const __attribute__((address_space(1))) void*)(g),
                                   (__attribute__((address_space(3))) void*)(l),
                                   16, 0, 0);
}

// ---------------- weight f32 [K][N] -> bf16 transposed [N][K] (optional scale) ----
__global__ __launch_bounds__(256)
void wconv_kernel(const float* __restrict__ W, u16* __restrict__ Wt, int K, int N,
                  float scale) {
  __shared__ u16 t[32][33];
  const int tid = threadIdx.x, tx = tid & 31, ty = tid >> 5;
  const int n0 = blockIdx.x * 32, k0 = blockIdx.y * 32;
#pragma unroll
  for (int i = 0; i < 4; ++i) {
    int k = ty + i * 8;
    t[k][tx] = f2bf(W[(size_t)(k0 + k) * N + n0 + tx] * scale);
  }
  __syncthreads();
#pragma unroll
  for (int i = 0; i < 4; ++i) {
    int n = ty + i * 8;
    Wt[(size_t)(n0 + n) * K + k0 + tx] = t[tx][n];
  }
}

// ---------------- layernorm: f32 [row][1024] -> bf16 ----------------
__global__ __launch_bounds__(256)
void ln_kernel(const float* __restrict__ x, u16* __restrict__ out,
               const float* __restrict__ g, const float* __restrict__ beta) {
  const int row = blockIdx.x, tid = threadIdx.x;
  const float4 v = reinterpret_cast<const float4*>(x + (size_t)row * D_MODEL)[tid];
  float s = v.x + v.y + v.z + v.w;
#pragma unroll
  for (int off = 32; off; off >>= 1) s += __shfl_down(s, off);
  __shared__ float red[8];
  if ((tid & 63) == 0) red[tid >> 6] = s;
  __syncthreads();
  const float mu = (red[0] + red[1] + red[2] + red[3]) * (1.0f / D_MODEL);
  const float dx = v.x - mu, dy = v.y - mu, dz = v.z - mu, dw = v.w - mu;
  float sq = dx * dx + dy * dy + dz * dz + dw * dw;
#pragma unroll
  for (int off = 32; off; off >>= 1) sq += __shfl_down(sq, off);
  if ((tid & 63) == 0) red[4 + (tid >> 6)] = sq;
  __syncthreads();
  const float var = (red[4] + red[5] + red[6] + red[7]) * (1.0f / D_MODEL);
  const float rs = rsqrtf(var + 1e-5f);
  const float4 gv = reinterpret_cast<const float4*>(g)[tid];
  const float4 bv = reinterpret_cast<const float4*>(beta)[tid];
  ushort4 ov;
  ov.x = f2bf(dx * rs * gv.x + bv.x);
  ov.y = f2bf(dy * rs * gv.y + bv.y);
  ov.z = f2bf(dz * rs * gv.z + bv.z);
  ov.w = f2bf(dw * rs * gv.w + bv.w);
  reinterpret_cast<ushort4*>(out + (size_t)row * D_MODEL)[tid] = ov;
}

// ---------------- TN GEMM: C[M,N] = A[M,K] * Bt[N,K]^T, bf16 in, epilogues ----
// EPI 0: C -> bf16 out (row-major [M][N])
// EPI 1: C + bias[col] + res[idx] -> f32 out   (res may alias out)
// EPI 2: relu(C + bias[col]) -> bf16 out
// EPI 3: C -> bf16 out TRANSPOSED per batch: out[(b*1024+col)*2048 + s], b=row>>11, s=row&2047
template <int EPI>
__global__ __launch_bounds__(256)
void gemm_kernel(const u16* __restrict__ A, const u16* __restrict__ Bt,
                 int N, int K,
                 const float* __restrict__ bias,
                 const float* __restrict__ res,
                 float* __restrict__ outf, u16* __restrict__ outb) {
  __shared__ u16 Al[128 * 64];
  __shared__ u16 Bl[128 * 64];
  const int tid = threadIdx.x;
  const int lane = tid & 63, wave = tid >> 6, g8 = lane >> 4, l16 = lane & 15;
  const int wr = wave >> 1, wc = wave & 1;
  const int mBase = blockIdx.y * 128, nBase = blockIdx.x * 128;
  const int ldCol = (lane & 7) * 8;   // 8 elems per lane within a 16B segment

  f32x4 acc[4][4];
#pragma unroll
  for (int i = 0; i < 4; ++i)
#pragma unroll
    for (int j = 0; j < 4; ++j) acc[i][j] = f32x4{0.f, 0.f, 0.f, 0.f};

  for (int k0 = 0; k0 < K; k0 += 64) {
    // wave w stages A rows [w*32, w*32+32) and B rows same, 4 issues each
#pragma unroll
    for (int i = 0; i < 4; ++i) {
      const int row = wave * 32 + i * 8 + (lane >> 3);
      gload16(A + (size_t)(mBase + row) * K + k0 + ldCol, &Al[(wave * 32 + i * 8) * 64]);
      gload16(Bt + (size_t)(nBase + row) * K + k0 + ldCol, &Bl[(wave * 32 + i * 8) * 64]);
    }
    __syncthreads();
#pragma unroll
    for (int ks = 0; ks < 2; ++ks) {
      bf16x8 af[4], bfr[4];
#pragma unroll
      for (int i = 0; i < 4; ++i) {
        af[i] = *reinterpret_cast<const bf16x8*>(&Al[(wr * 64 + i * 16 + l16) * 64 + ks * 32 + g8 * 8]);
        bfr[i] = *reinterpret_cast<const bf16x8*>(&Bl[(wc * 64 + i * 16 + l16) * 64 + ks * 32 + g8 * 8]);
      }
#pragma unroll
      for (int i = 0; i < 4; ++i)
#pragma unroll
        for (int j = 0; j < 4; ++j)
          acc[i][j] = __builtin_amdgcn_mfma_f32_16x16x32_bf16(af[i], bfr[j], acc[i][j], 0, 0, 0);
    }
    __syncthreads();
  }

#pragma unroll
  for (int i = 0; i < 4; ++i)
#pragma unroll
    for (int j = 0; j < 4; ++j) {
      const int col = nBase + wc * 64 + j * 16 + l16;
      float bv = 0.f;
      if (EPI == 1 || EPI == 2) bv = bias[col];
      if (EPI == 3) {
        const int s0 = mBase + wr * 64 + i * 16 + g8 * 4;
        const int bi = s0 >> 11, s = s0 & 2047;
        ushort4 pk;
        pk.x = f2bf(acc[i][j][0]);
        pk.y = f2bf(acc[i][j][1]);
        pk.z = f2bf(acc[i][j][2]);
        pk.w = f2bf(acc[i][j][3]);
        *reinterpret_cast<ushort4*>(outb + ((size_t)(bi << 10) + col) * SEQ + s) = pk;
      } else {
#pragma unroll
        for (int r = 0; r < 4; ++r) {
          const int row = mBase + wr * 64 + i * 16 + g8 * 4 + r;
          const size_t idx = (size_t)row * N + col;
          const float vv = acc[i][j][r];
          if (EPI == 0) {
            outb[idx] = f2bf(vv);
          } else if (EPI == 1) {
            outf[idx] = vv + bv + res[idx];
          } else {
            const float tv = vv + bv;
            outb[idx] = f2bf(tv > 0.f ? tv : 0.f);
          }
        }
      }
    }
}

// ---------------- flash attention, 4 waves x 32 q-rows, KV tile 64 ----------------
// Swapped QK^T: S^T = mfma(K_frag, Q_frag) -> each lane holds q = l16, kv = kt*16+g8*4+r.
// Softmax reduction: 15 in-reg fmax/add + 2 shfl_xor (16,32). P write: ushort4 per (m,kt).
// qb pre-scaled by 1/8 (folded into wq). vb is V^T per batch: vb[(b*1024+h*64+d)*2048+s].
__global__ __launch_bounds__(256)
void attn_kernel(const u16* __restrict__ qb, const u16* __restrict__ kb,
                 const u16* __restrict__ vb, u16* __restrict__ ctx) {
  __shared__ u16 Kl[64 * LDST];
  __shared__ u16 Vl[64 * LDST];        // V^T tile: Vl[d][t]
  __shared__ u16 Pl[4][32 * LDST];     // per-wave P: [q 32][kv 64]
  const int tid = threadIdx.x;
  const int lane = tid & 63, wave = tid >> 6, g8 = lane >> 4, l16 = lane & 15;
  const int b = blockIdx.y >> 4, h = blockIdx.y & 15;
  const int q0 = blockIdx.x * 128 + wave * 32;
  const size_t rowB = (size_t)b * SEQ;
  const int colH = h * DH;
  const size_t vtBase = (size_t)(b * 1024 + colH) * SEQ;

  bf16x8 qf[2][2];
#pragma unroll
  for (int m = 0; m < 2; ++m)
#pragma unroll
    for (int ks = 0; ks < 2; ++ks)
      qf[m][ks] = *reinterpret_cast<const bf16x8*>(
          qb + (rowB + q0 + m * 16 + l16) * D_MODEL + colH + ks * 32 + g8 * 8);

  // per-lane online-softmax state for q = m*16 + l16
  float mi[2] = {-1e30f, -1e30f}, li[2] = {0.f, 0.f};
  f32x4 o[2][4];  // o[m][nt]: C[q = m*16 + g8*4+r][d = nt*16 + l16]
#pragma unroll
  for (int m = 0; m < 2; ++m)
#pragma unroll
    for (int nt = 0; nt < 4; ++nt) o[m][nt] = f32x4{0.f, 0.f, 0.f, 0.f};

  const int srow = tid >> 3, scol = (tid & 7) * 8;

  for (int t0 = 0; t0 < SEQ; t0 += 64) {
#pragma unroll
    for (int i = 0; i < 2; ++i) {
      const int row = srow + i * 32;
      *reinterpret_cast<int4*>(&Kl[row * LDST + scol]) =
          *reinterpret_cast<const int4*>(kb + (rowB + t0 + row) * D_MODEL + colH + scol);
      *reinterpret_cast<int4*>(&Vl[row * LDST + scol]) =
          *reinterpret_cast<const int4*>(vb + vtBase + (size_t)row * SEQ + t0 + scol);
    }
    __syncthreads();

    // S^T tiles: st[m][kt], rows kv = kt*16+g8*4+r, cols q = m*16+l16
    f32x4 st[2][4];
#pragma unroll
    for (int m = 0; m < 2; ++m)
#pragma unroll
      for (int kt = 0; kt < 4; ++kt) st[m][kt] = f32x4{0.f, 0.f, 0.f, 0.f};
#pragma unroll
    for (int kt = 0; kt < 4; ++kt) {
      const bf16x8 kf0 = *reinterpret_cast<const bf16x8*>(&Kl[(kt * 16 + l16) * LDST + g8 * 8]);
      const bf16x8 kf1 = *reinterpret_cast<const bf16x8*>(&Kl[(kt * 16 + l16) * LDST + 32 + g8 * 8]);
#pragma unroll
      for (int m = 0; m < 2; ++m) {
        st[m][kt] = __builtin_amdgcn_mfma_f32_16x16x32_bf16(kf0, qf[m][0], st[m][kt], 0, 0, 0);
        st[m][kt] = __builtin_amdgcn_mfma_f32_16x16x32_bf16(kf1, qf[m][1], st[m][kt], 0, 0, 0);
      }
    }

    float alpha[2];
#pragma unroll
    for (int m = 0; m < 2; ++m) {
      // row max over this tile's 64 kv for q = m*16+l16
      float pmax = st[m][0][0];
#pragma unroll
      for (int kt = 0; kt < 4; ++kt)
#pragma unroll
        for (int r = 0; r < 4; ++r) pmax = fmaxf(pmax, st[m][kt][r]);
      pmax = fmaxf(pmax, __shfl_xor(pmax, 16));
      pmax = fmaxf(pmax, __shfl_xor(pmax, 32));
      const float mnew = fmaxf(mi[m], pmax);
      alpha[m] = __expf(mi[m] - mnew);
      mi[m] = mnew;
      float sum = 0.f;
#pragma unroll
      for (int kt = 0; kt < 4; ++kt) {
        ushort4 pk;
#pragma unroll
        for (int r = 0; r < 4; ++r) {
          const float p = __expf(st[m][kt][r] - mnew);
          sum += p;
          ((u16*)&pk)[r] = f2bf(p);
        }
        *reinterpret_cast<ushort4*>(&Pl[wave][(m * 16 + l16) * LDST + kt * 16 + g8 * 4]) = pk;
      }
      sum += __shfl_xor(sum, 16);
      sum += __shfl_xor(sum, 32);
      li[m] = li[m] * alpha[m] + sum;
    }

    // rescale o: alpha needed at q = g8*4+r -> broadcast from lane g8*4+r
#pragma unroll
    for (int m = 0; m < 2; ++m) {
      f32x4 al;
#pragma unroll
      for (int r = 0; r < 4; ++r) al[r] = __shfl(alpha[m], g8 * 4 + r);
#pragma unroll
      for (int nt = 0; nt < 4; ++nt) {
        f32x4 t = o[m][nt];
        t[0] *= al[0]; t[1] *= al[1]; t[2] *= al[2]; t[3] *= al[3];
        o[m][nt] = t;
      }
    }

    // O += P V  (P A-frags from per-wave LDS; V^T B-frags vector reads)
    bf16x8 pf[2][2];
#pragma unroll
    for (int m = 0; m < 2; ++m)
#pragma unroll
      for (int ks = 0; ks < 2; ++ks)
        pf[m][ks] = *reinterpret_cast<const bf16x8*>(&Pl[wave][(m * 16 + l16) * LDST + ks * 32 + g8 * 8]);
#pragma unroll
    for (int nt = 0; nt < 4; ++nt) {
      const bf16x8 vf0 = *reinterpret_cast<const bf16x8*>(&Vl[(nt * 16 + l16) * LDST + g8 * 8]);
      const bf16x8 vf1 = *reinterpret_cast<const bf16x8*>(&Vl[(nt * 16 + l16) * LDST + 32 + g8 * 8]);
#pragma unroll
      for (int m = 0; m < 2; ++m) {
        o[m][nt] = __builtin_amdgcn_mfma_f32_16x16x32_bf16(pf[m][0], vf0, o[m][nt], 0, 0, 0);
        o[m][nt] = __builtin_amdgcn_mfma_f32_16x16x32_bf16(pf[m][1], vf1, o[m][nt], 0, 0, 0);
      }
    }
    __syncthreads();
  }

#pragma unroll
  for (int m = 0; m < 2; ++m) {
    f32x4 ld;
#pragma unroll
    for (int r = 0; r < 4; ++r) ld[r] = 1.0f / __shfl(li[m], g8 * 4 + r);
#pragma unroll
    for (int nt = 0; nt < 4; ++nt)
#pragma unroll
      for (int r = 0; r < 4; ++r) {
        const float v = o[m][nt][r] * ld[r];
        ctx[(rowB + q0 + m * 16 + g8 * 4 + r) * D_MODEL + colH + nt * 16 + l16] = f2bf(v);
      }
  }
}

extern "C" void kernel_launch(void* const* d_in, const int* in_sizes, int n_in,
                              void* d_out, int out_size, void* d_ws, size_t ws_size,
                              hipStream_t stream) {
  const float* x   = (const float*)d_in[0];
  const float* wq  = (const float*)d_in[1];
  const float* wk  = (const float*)d_in[2];
  const float* wv  = (const float*)d_in[3];
  const float* wo  = (const float*)d_in[4];
  const float* bo  = (const float*)d_in[5];
  const float* l1g = (const float*)d_in[6];
  const float* l1b = (const float*)d_in[7];
  const float* l2g = (const float*)d_in[8];
  const float* l2b = (const float*)d_in[9];
  const float* w1  = (const float*)d_in[10];
  const float* b1  = (const float*)d_in[11];
  const float* w2  = (const float*)d_in[12];
  const float* b2  = (const float*)d_in[13];
  float* outp = (float*)d_out;

  uint8_t* ws = (uint8_t*)d_ws;
  const size_t MB = 1024 * 1024;
  // workspace layout (120 MB total, lifetime-based overlays):
  u16* wqt   = (u16*)(ws + 0 * MB);   // [1024][1024]
  u16* wkt   = (u16*)(ws + 2 * MB);
  u16* wvt   = (u16*)(ws + 4 * MB);
  u16* wot   = (u16*)(ws + 6 * MB);
  u16* w1t   = (u16*)(ws + 8 * MB);   // [4096][1024]
  u16* w2t   = (u16*)(ws + 16 * MB);  // [1024][4096]
  u16* xn    = (u16*)(ws + 24 * MB);  // [8192][1024]; reused as ctx after QKV
  u16* qbuf  = (u16*)(ws + 40 * MB);  // [8192][1024]; reused as h after attention
  u16* kbuf  = (u16*)(ws + 56 * MB);  // [8192][1024]
  u16* vbufT = (u16*)(ws + 72 * MB);  // [4][1024][2048] transposed V
  u16* ctx   = xn;
  u16* hbuf  = qbuf;
  u16* ffh   = kbuf;                  // [8192][4096] overlays kbuf..(56+64) MB (vbufT dead by then)

  dim3 blk(256);

  // weights -> bf16 transposed; wq carries the 1/sqrt(Dh)=0.125 attention scale (pow2: exact)
  wconv_kernel<<<dim3(32, 32), blk, 0, stream>>>(wq, wqt, 1024, 1024, 0.125f);
  wconv_kernel<<<dim3(32, 32), blk, 0, stream>>>(wk, wkt, 1024, 1024, 1.0f);
  wconv_kernel<<<dim3(32, 32), blk, 0, stream>>>(wv, wvt, 1024, 1024, 1.0f);
  wconv_kernel<<<dim3(32, 32), blk, 0, stream>>>(wo, wot, 1024, 1024, 1.0f);
  wconv_kernel<<<dim3(128, 32), blk, 0, stream>>>(w1, w1t, 1024, 4096, 1.0f);
  wconv_kernel<<<dim3(32, 128), blk, 0, stream>>>(w2, w2t, 4096, 1024, 1.0f);

  // xn = LN1(x)
  ln_kernel<<<MROWS, blk, 0, stream>>>(x, xn, l1g, l1b);

  // q, k projections row-major; v projection written transposed per head
  gemm_kernel<0><<<dim3(8, 64), blk, 0, stream>>>(xn, wqt, 1024, 1024, nullptr, nullptr, nullptr, qbuf);
  gemm_kernel<0><<<dim3(8, 64), blk, 0, stream>>>(xn, wkt, 1024, 1024, nullptr, nullptr, nullptr, kbuf);
  gemm_kernel<3><<<dim3(8, 64), blk, 0, stream>>>(xn, wvt, 1024, 1024, nullptr, nullptr, nullptr, vbufT);

  // ctx = softmax(QK^T/8) V
  attn_kernel<<<dim3(16, 64), blk, 0, stream>>>(qbuf, kbuf, vbufT, ctx);

  // xt = x + ctx@wo + bo   (-> d_out, f32)
  gemm_kernel<1><<<dim3(8, 64), blk, 0, stream>>>(ctx, wot, 1024, 1024, bo, x, outp, nullptr);

  // h = LN2(xt)
  ln_kernel<<<MROWS, blk, 0, stream>>>(outp, hbuf, l2g, l2b);

  // ffh = relu(h@w1 + b1)
  gemm_kernel<2><<<dim3(32, 64), blk, 0, stream>>>(hbuf, w1t, 4096, 1024, b1, nullptr, nullptr, ffh);

  // out = xt + ffh@w2 + b2  (in-place on d_out)
  gemm_kernel<1><<<dim3(8, 64), blk, 0, stream>>>(ffh, w2t, 1024, 4096, b2, outp, outp, nullptr);
}